// Round 7
// baseline (8048.939 us; speedup 1.0000x reference)
//
#include <hip/hip_runtime.h>
#include <hip/hip_bf16.h>

#define Bn 64
#define Sn 256
#define Cn 512
#define Hn 1024
#define On 1024
#define NL 3

// ------------------------------------------------------------------
// prep: h0T[l][k][b] = hid[b][l+1][k]  (64x64 LDS tile transpose)
// ------------------------------------------------------------------
__global__ __launch_bounds__(256) void prep_kernel(const float* __restrict__ hid,
                                                   float* __restrict__ h0T) {
    __shared__ float T[64][65];
    int l = blockIdx.x >> 4;
    int kb = (blockIdx.x & 15) * 64;
    int tid = threadIdx.x;
    for (int e = tid; e < 1024; e += 256) {
        int b = e >> 4, k4 = (e & 15) * 4;
        float4 v = *(const float4*)&hid[(size_t)b * 4096 + (size_t)(l + 1) * 1024 + kb + k4];
        T[b][k4] = v.x; T[b][k4 + 1] = v.y; T[b][k4 + 2] = v.z; T[b][k4 + 3] = v.w;
    }
    __syncthreads();
    for (int e = tid; e < 1024; e += 256) {
        int k = e >> 4, b4 = (e & 15) * 4;
        float4 v = make_float4(T[b4][k], T[b4 + 1][k], T[b4 + 2][k], T[b4 + 3][k]);
        *(float4*)&h0T[(size_t)l * 65536 + (size_t)(kb + k) * 64 + b4] = v;
    }
}

// ------------------------------------------------------------------
// G1: h0proj[b][g] = fc1_b[g] + sum_h h0[b][h] * fc1_w[g][512+h]
// ------------------------------------------------------------------
__global__ __launch_bounds__(256) void g1_kernel(const float* __restrict__ hid,
                                                 const float* __restrict__ fc1_w,
                                                 const float* __restrict__ fc1_b,
                                                 float* __restrict__ h0proj) {
    __shared__ __align__(16) float h0s[Hn];
    int b = blockIdx.x;
    int tid = threadIdx.x;
    for (int i = tid; i < Hn; i += 256) h0s[i] = hid[(size_t)b * 4 * Hn + i];
    __syncthreads();
    for (int g = tid; g < Hn; g += 256) {
        const float* wr = fc1_w + (size_t)g * (Cn + Hn) + Cn;
        float acc = 0.f;
        for (int k = 0; k < Hn; k += 4) {
            float4 w4 = *(const float4*)&wr[k];
            acc = fmaf(w4.x, h0s[k + 0], acc);
            acc = fmaf(w4.y, h0s[k + 1], acc);
            acc = fmaf(w4.z, h0s[k + 2], acc);
            acc = fmaf(w4.w, h0s[k + 3], acc);
        }
        h0proj[b * Hn + g] = acc + fc1_b[g];
    }
}

// ------------------------------------------------------------------
// G2: tb[t][g][b] = bf16( tanh( X[t,b,:512]@fc1_w[g,:512] + h0proj[b][g] ) )
// ------------------------------------------------------------------
__global__ __launch_bounds__(256) void g2_kernel(const float* __restrict__ x,
                                                 const float* __restrict__ fc1_w,
                                                 const float* __restrict__ h0proj,
                                                 __hip_bfloat16* __restrict__ tb) {
    __shared__ __align__(16) float As[64][64];
    __shared__ __align__(16) float Bs[64][64];
    int tid = threadIdx.x;
    int bx = blockIdx.x;
    int g0 = blockIdx.y * 64;
    int ml = tid & 63;
    int kq = tid >> 6;
    const float* xrow = x + (size_t)ml * (Sn * Cn) + (size_t)bx * Cn;
    const float* wrow = fc1_w + (size_t)(g0 + ml) * (Cn + Hn);
    int wave = tid >> 6, lane = tid & 63;
    int tm = (wave & 1) * 32 + (lane & 7) * 4;
    int tg = (wave >> 1) * 32 + (lane >> 3) * 4;
    float acc[4][4] = {};
    for (int kc = 0; kc < Cn / 64; ++kc) {
#pragma unroll
        for (int r = 0; r < 4; ++r) {
            int kk = kq * 16 + r * 4;
            float4 v = *(const float4*)&xrow[kc * 64 + kk];
            As[kk + 0][ml] = v.x; As[kk + 1][ml] = v.y;
            As[kk + 2][ml] = v.z; As[kk + 3][ml] = v.w;
        }
#pragma unroll
        for (int r = 0; r < 4; ++r) {
            int kk = kq * 16 + r * 4;
            float4 v = *(const float4*)&wrow[kc * 64 + kk];
            Bs[kk + 0][ml] = v.x; Bs[kk + 1][ml] = v.y;
            Bs[kk + 2][ml] = v.z; Bs[kk + 3][ml] = v.w;
        }
        __syncthreads();
#pragma unroll 4
        for (int k = 0; k < 64; ++k) {
            float4 a4 = *(const float4*)&As[k][tm];
            float4 b4 = *(const float4*)&Bs[k][tg];
            float av[4] = {a4.x, a4.y, a4.z, a4.w};
            float bv[4] = {b4.x, b4.y, b4.z, b4.w};
#pragma unroll
            for (int i = 0; i < 4; ++i)
#pragma unroll
                for (int j = 0; j < 4; ++j)
                    acc[i][j] = fmaf(av[i], bv[j], acc[i][j]);
        }
        __syncthreads();
    }
#pragma unroll
    for (int j = 0; j < 4; ++j) {
        int g = g0 + tg + j;
        union { ushort4 u4; __hip_bfloat16 h[4]; } cv;
#pragma unroll
        for (int i = 0; i < 4; ++i) {
            float hp = h0proj[(size_t)(tm + i) * Hn + g];
            cv.h[i] = __float2bfloat16(tanhf(acc[i][j] + hp));
        }
        *(ushort4*)&tb[((size_t)bx * Hn + g) * 64 + tm] = cv.u4;
    }
}

// ------------------------------------------------------------------
// G3: logits[m][o] = relu( temp[m][:] @ fc2_w[o][:] + fc2_b[o] )
// ------------------------------------------------------------------
__global__ __launch_bounds__(256) void g3_kernel(const __hip_bfloat16* __restrict__ tb,
                                                 const float* __restrict__ fc2_w,
                                                 const float* __restrict__ fc2_b,
                                                 float* __restrict__ logits) {
    __shared__ __align__(16) float As[64][64];
    __shared__ __align__(16) float Bs[64][64];
    int tid = threadIdx.x;
    int bx = blockIdx.x;
    int g0 = blockIdx.y * 64;
    int ml = tid & 63;
    int kq = tid >> 6;
    const float* wrow = fc2_w + (size_t)(g0 + ml) * Hn;
    int wave = tid >> 6, lane = tid & 63;
    int tm = (wave & 1) * 32 + (lane & 7) * 4;
    int tg = (wave >> 1) * 32 + (lane >> 3) * 4;
    float acc[4][4] = {};
    for (int kc = 0; kc < Hn / 64; ++kc) {
        for (int e = tid; e < 4096; e += 256) {
            int kk = e >> 6, mm = e & 63;
            As[kk][mm] = __bfloat162float(tb[((size_t)bx * Hn + kc * 64 + kk) * 64 + mm]);
        }
#pragma unroll
        for (int r = 0; r < 4; ++r) {
            int kk = kq * 16 + r * 4;
            float4 v = *(const float4*)&wrow[kc * 64 + kk];
            Bs[kk + 0][ml] = v.x; Bs[kk + 1][ml] = v.y;
            Bs[kk + 2][ml] = v.z; Bs[kk + 3][ml] = v.w;
        }
        __syncthreads();
#pragma unroll 4
        for (int k = 0; k < 64; ++k) {
            float4 a4 = *(const float4*)&As[k][tm];
            float4 b4 = *(const float4*)&Bs[k][tg];
            float av[4] = {a4.x, a4.y, a4.z, a4.w};
            float bv[4] = {b4.x, b4.y, b4.z, b4.w};
#pragma unroll
            for (int i = 0; i < 4; ++i)
#pragma unroll
                for (int j = 0; j < 4; ++j)
                    acc[i][j] = fmaf(av[i], bv[j], acc[i][j]);
        }
        __syncthreads();
    }
    int m0 = bx * 64;
#pragma unroll
    for (int i = 0; i < 4; ++i) {
        int m = m0 + tm + i;
        float4 o;
        o.x = fmaxf(acc[i][0] + fc2_b[g0 + tg + 0], 0.f);
        o.y = fmaxf(acc[i][1] + fc2_b[g0 + tg + 1], 0.f);
        o.z = fmaxf(acc[i][2] + fc2_b[g0 + tg + 2], 0.f);
        o.w = fmaxf(acc[i][3] + fc2_b[g0 + tg + 3], 0.f);
        *(float4*)&logits[(size_t)m * Hn + g0 + tg] = o;
    }
}

// ------------------------------------------------------------------
// cvec: out[r] = sum_m A[r][m] * vecB[l(r)*1024 + m] + addB[r]
// ------------------------------------------------------------------
__global__ __launch_bounds__(256) void cvec_kernel(const float* __restrict__ A,
                                                   const float* __restrict__ vecB,
                                                   const float* __restrict__ addB,
                                                   float* __restrict__ outv) {
    int row = blockIdx.x * 4 + (threadIdx.x >> 6);
    int lane = threadIdx.x & 63;
    int l = row >> 10;
    const float* ar = A + (size_t)row * Hn;
    const float* vb = vecB + (size_t)l * Hn;
    float s = 0.f;
#pragma unroll 4
    for (int j = 0; j < 16; ++j) {
        int k = lane + j * 64;
        s = fmaf(ar[k], vb[k], s);
    }
    s += __shfl_xor(s, 1);  s += __shfl_xor(s, 2);  s += __shfl_xor(s, 4);
    s += __shfl_xor(s, 8);  s += __shfl_xor(s, 16); s += __shfl_xor(s, 32);
    if (lane == 0) outv[row] = s + addB[row];
}

// ==================================================================
// gsl2<NC>: C[3072 x NC] = A(16 rows/WG, uniform s_loads) * B (+addRow)
// 192 WGs x 512 thr; layer-clean 16 rows; thread tile 8r x 2c.
// B: 2 x (16k x NC) LDS dbuf, T14 reg-prefetch (512-cy compute window).
// XCD banding: contiguous 384-row band per XCD -> X panels L2-resident.
// Optional fused fold batch (8 timesteps) at head.
// ==================================================================
template<int NC>
__global__ __launch_bounds__(512, 2) void gsl2_kernel(
        const float* __restrict__ A,          // [3072][1024] flat
        const float* __restrict__ Bsrc,       // + l*bPanel + k*bstride + bcol0
        unsigned long long bPanel, int bstride, int bcol0,
        float* __restrict__ dst, int dstride, int dcol0,
        const float* __restrict__ addRow,     // [3072] or nullptr
        __hip_bfloat16* __restrict__ tb, const float* __restrict__ Xf,
        int folds, int do_gemm) {
    __shared__ __align__(16) float Bsh[2][16][NC];
    const int tid = threadIdx.x;
    const int bid = blockIdx.x;
    const int lbid = (bid & 7) * 24 + (bid >> 3);   // XCD-contiguous band
    const int row0 = lbid * 16;
    const int l = row0 >> 10;

    // ---- fused fold(t = 8*folds + tp): temp = tanh(h2+tanh(h1+tanh(h0+t0))) ----
    if (folds >= 0) {
        for (int e = bid * 512 + tid; e < 8 * Hn * Bn; e += 192 * 512) {
            int b = e & 63, g = (e >> 6) & 1023, tp = e >> 16;
            int c = tp * 64 + b;
            size_t tix = ((size_t)(8 * folds + tp) * Hn + g) * 64 + b;
            float tv = __bfloat162float(tb[tix]);
            tv = tanhf(Xf[(size_t)g * 512 + c] + tv);
            tv = tanhf(Xf[524288 + (size_t)g * 512 + c] + tv);
            tv = tanhf(Xf[1048576 + (size_t)g * 512 + c] + tv);
            tb[tix] = __float2bfloat16(tv);
        }
    }
    if (!do_gemm) return;

    const int rq = tid >> 8;                  // 0..1 (wave-uniform)
    const int cq = tid & 255;
    const int rbase = __builtin_amdgcn_readfirstlane(row0 + rq * 8);
    const float* __restrict__ A8 = A + (size_t)rbase * 1024;
    const float* __restrict__ Bp = Bsrc + (size_t)l * bPanel + bcol0;
    constexpr int NF4 = NC / 4;               // float4 per k-row
    constexpr int TOT4 = 16 * NF4;            // float4 per chunk
    constexpr int PFN = (TOT4 + 511) / 512;
    const bool cact = (2 * cq < NC);

    float acc[8][2] = {};
    float4 pf[PFN];

    // stage chunk 0
#pragma unroll
    for (int i = 0; i < PFN; ++i) {
        int e = tid + i * 512;
        if ((TOT4 % 512 == 0) || e < TOT4) {
            int k = e / NF4, c4 = e % NF4;
            pf[i] = *(const float4*)(Bp + (size_t)k * bstride + c4 * 4);
        }
    }
#pragma unroll
    for (int i = 0; i < PFN; ++i) {
        int e = tid + i * 512;
        if ((TOT4 % 512 == 0) || e < TOT4) {
            int k = e / NF4, c4 = e % NF4;
            *(float4*)&Bsh[0][k][c4 * 4] = pf[i];
        }
    }
    __syncthreads();

    for (int ck = 0; ck < 64; ++ck) {
        if (ck < 63) {                        // T14: issue next-chunk loads early
#pragma unroll
            for (int i = 0; i < PFN; ++i) {
                int e = tid + i * 512;
                if ((TOT4 % 512 == 0) || e < TOT4) {
                    int k = e / NF4, c4 = e % NF4;
                    pf[i] = *(const float4*)(Bp + (size_t)((ck + 1) * 16 + k) * bstride + c4 * 4);
                }
            }
        }
        if (cact) {
            const float* bsc = &Bsh[ck & 1][0][2 * cq];
            const int k0 = ck * 16;
#pragma unroll
            for (int kk = 0; kk < 16; ++kk) {
                float2 b2 = *(const float2*)(bsc + kk * NC);
                const float* Ap = A8 + k0 + kk;
#pragma unroll
                for (int i = 0; i < 8; ++i) {
                    float av = Ap[(size_t)i * 1024];
                    acc[i][0] = fmaf(av, b2.x, acc[i][0]);
                    acc[i][1] = fmaf(av, b2.y, acc[i][1]);
                }
            }
        }
        if (ck < 63) {
#pragma unroll
            for (int i = 0; i < PFN; ++i) {
                int e = tid + i * 512;
                if ((TOT4 % 512 == 0) || e < TOT4) {
                    int k = e / NF4, c4 = e % NF4;
                    *(float4*)&Bsh[(ck + 1) & 1][k][c4 * 4] = pf[i];
                }
            }
            __syncthreads();
        }
    }

    if (cact) {
#pragma unroll
        for (int i = 0; i < 8; ++i) {
            int r = rbase + i;
            float av = addRow ? addRow[r] : 0.0f;
            float2 o = make_float2(acc[i][0] + av, acc[i][1] + av);
            *(float2*)(dst + (size_t)r * dstride + dcol0 + 2 * cq) = o;
        }
    }
}

// ------------------------------------------------------------------
// softmax over each 1024-row of logits -> f32 out
// ------------------------------------------------------------------
__global__ __launch_bounds__(256) void softmax_kernel(const float* __restrict__ logits,
                                                      float* __restrict__ out) {
    __shared__ float redm[4];
    __shared__ float reds[4];
    __shared__ float bcast[2];
    int row = blockIdx.x, tid = threadIdx.x;
    const float* in = logits + (size_t)row * On;
    float4 v = *(const float4*)&in[tid * 4];
    float mx = fmaxf(fmaxf(v.x, v.y), fmaxf(v.z, v.w));
#pragma unroll
    for (int o = 32; o > 0; o >>= 1) mx = fmaxf(mx, __shfl_down(mx, o));
    if ((tid & 63) == 0) redm[tid >> 6] = mx;
    __syncthreads();
    if (tid == 0) bcast[0] = fmaxf(fmaxf(redm[0], redm[1]), fmaxf(redm[2], redm[3]));
    __syncthreads();
    float M = bcast[0];
    float e0 = expf(v.x - M), e1 = expf(v.y - M), e2 = expf(v.z - M), e3 = expf(v.w - M);
    float s = e0 + e1 + e2 + e3;
#pragma unroll
    for (int o = 32; o > 0; o >>= 1) s += __shfl_down(s, o);
    if ((tid & 63) == 0) reds[tid >> 6] = s;
    __syncthreads();
    if (tid == 0) bcast[1] = reds[0] + reds[1] + reds[2] + reds[3];
    __syncthreads();
    float inv = 1.0f / bcast[1];
    float4 o4 = make_float4(e0 * inv, e1 * inv, e2 * inv, e3 * inv);
    *(float4*)&out[(size_t)row * On + tid * 4] = o4;
}

// ------------------------------------------------------------------
extern "C" void kernel_launch(void* const* d_in, const int* in_sizes, int n_in,
                              void* d_out, int out_size, void* d_ws, size_t ws_size,
                              hipStream_t stream) {
    const float* x     = (const float*)d_in[0];
    const float* hid   = (const float*)d_in[1];
    const float* fc1_w = (const float*)d_in[2];
    const float* fc1_b = (const float*)d_in[3];
    const float* fc2_w = (const float*)d_in[4];
    const float* fc2_b = (const float*)d_in[5];
    const float* lin_w = (const float*)d_in[6];
    const float* lin_b = (const float*)d_in[7];
    float* out = (float*)d_out;

    char* wsb = (char*)d_ws;
    __hip_bfloat16* tb = (__hip_bfloat16*)wsb;            // [0, 32MB)
    // recurrence scratch region (dead before g3) overlaid by logits:
    float* w2     = (float*)(wsb + 33554432ull);          // 12 MB
    float* w4     = (float*)(wsb + 46137344ull);          // 12 MB
    float* w8     = (float*)(wsb + 58720256ull);          // 12 MB
    float* X0     = (float*)(wsb + 71303168ull);          // 6 MB [l][g][512]
    float* X1     = (float*)(wsb + 77594624ull);          // 6 MB
    float* c2     = (float*)(wsb + 83886080ull);          // 12 KB
    float* c4     = (float*)(wsb + 83898368ull);          // 12 KB
    float* c8     = (float*)(wsb + 83910656ull);          // 12 KB
    float* h0T    = (float*)(wsb + 83922944ull);          // 768 KB [l][k][64]
    float* h0proj = (float*)(wsb + 84709376ull);          // 256 KB
    float* logits = (float*)(wsb + 33554432ull);          // 64 MB (overlay, used after)

    prep_kernel<<<48, 256, 0, stream>>>(hid, h0T);
    g1_kernel<<<Bn, 256, 0, stream>>>(hid, fc1_w, fc1_b, h0proj);
    g2_kernel<<<dim3(Sn, Hn / 64), 256, 0, stream>>>(x, fc1_w, h0proj, tb);

    // ---- powers & c-vectors ----
    cvec_kernel<<<768, 256, 0, stream>>>(lin_w, lin_b, lin_b, c2);          // c2 = Wb+b
    for (int p = 0; p < 2; ++p)                                             // W2 = W*W
        gsl2_kernel<512><<<192, 512, 0, stream>>>(lin_w, lin_w, 1048576ull, 1024, p * 512,
                                                  w2, 1024, p * 512, nullptr,
                                                  tb, nullptr, -1, 1);
    cvec_kernel<<<768, 256, 0, stream>>>(w2, c2, c2, c4);                   // c4 = W2c2+c2
    for (int p = 0; p < 2; ++p)                                             // W4 = W2*W2
        gsl2_kernel<512><<<192, 512, 0, stream>>>(w2, w2, 1048576ull, 1024, p * 512,
                                                  w4, 1024, p * 512, nullptr,
                                                  tb, nullptr, -1, 1);
    cvec_kernel<<<768, 256, 0, stream>>>(w4, c4, c4, c8);                   // c8 = W4c4+c4
    for (int p = 0; p < 2; ++p)                                             // W8 = W4*W4
        gsl2_kernel<512><<<192, 512, 0, stream>>>(w4, w4, 1048576ull, 1024, p * 512,
                                                  w8, 1024, p * 512, nullptr,
                                                  tb, nullptr, -1, 1);

    // ---- seeds: X0 = [h1|h2|h3|h4|h5|h6|h7|h8] (64-col blocks) ----
    gsl2_kernel<64><<<192, 512, 0, stream>>>(lin_w, h0T, 65536ull, 64, 0,
                                             X0, 512, 0, lin_b, tb, nullptr, -1, 1);   // h1
    gsl2_kernel<64><<<192, 512, 0, stream>>>(w2, h0T, 65536ull, 64, 0,
                                             X0, 512, 64, c2, tb, nullptr, -1, 1);     // h2
    gsl2_kernel<64><<<192, 512, 0, stream>>>(w4, h0T, 65536ull, 64, 0,
                                             X0, 512, 192, c4, tb, nullptr, -1, 1);    // h4
    gsl2_kernel<64><<<192, 512, 0, stream>>>(w2, X0, 524288ull, 512, 0,
                                             X0, 512, 128, c2, tb, nullptr, -1, 1);    // h3=W2h1+c2
    gsl2_kernel<256><<<192, 512, 0, stream>>>(w4, X0, 524288ull, 512, 0,
                                              X0, 512, 256, c4, tb, nullptr, -1, 1);   // h5..h8

    // ---- main: 31 supersteps X_{s+1} = W8 X_s + c8, fused fold(batch s) ----
    for (int s = 0; s < 31; ++s) {
        float* Xin  = (s & 1) ? X1 : X0;
        float* Xout = (s & 1) ? X0 : X1;
        gsl2_kernel<512><<<192, 512, 0, stream>>>(w8, Xin, 524288ull, 512, 0,
                                                  Xout, 512, 0, c8, tb, Xin, s, 1);
    }
    // final fold batch 31 (state X_31 lives in X1)
    gsl2_kernel<512><<<192, 512, 0, stream>>>(w8, X1, 524288ull, 512, 0,
                                              X0, 512, 0, c8, tb, X1, 31, 0);

    g3_kernel<<<dim3(Sn, Hn / 64), 256, 0, stream>>>(tb, fc2_w, fc2_b, logits);
    softmax_kernel<<<Sn * Bn, 256, 0, stream>>>(logits, out);
}

// Round 8
// 7129.794 us; speedup vs baseline: 1.1289x; 1.1289x over previous
//
#include <hip/hip_runtime.h>
#include <hip/hip_bf16.h>

#define Bn 64
#define Sn 256
#define Cn 512
#define Hn 1024
#define On 1024
#define NL 3

// ------------------------------------------------------------------
// prep: h0T[l][k][b] = hid[b][l+1][k]  (64x64 LDS tile transpose)
// ------------------------------------------------------------------
__global__ __launch_bounds__(256) void prep_kernel(const float* __restrict__ hid,
                                                   float* __restrict__ h0T) {
    __shared__ float T[64][65];
    int l = blockIdx.x >> 4;
    int kb = (blockIdx.x & 15) * 64;
    int tid = threadIdx.x;
    for (int e = tid; e < 1024; e += 256) {
        int b = e >> 4, k4 = (e & 15) * 4;
        float4 v = *(const float4*)&hid[(size_t)b * 4096 + (size_t)(l + 1) * 1024 + kb + k4];
        T[b][k4] = v.x; T[b][k4 + 1] = v.y; T[b][k4 + 2] = v.z; T[b][k4 + 3] = v.w;
    }
    __syncthreads();
    for (int e = tid; e < 1024; e += 256) {
        int k = e >> 4, b4 = (e & 15) * 4;
        float4 v = make_float4(T[b4][k], T[b4 + 1][k], T[b4 + 2][k], T[b4 + 3][k]);
        *(float4*)&h0T[(size_t)l * 65536 + (size_t)(kb + k) * 64 + b4] = v;
    }
}

// ------------------------------------------------------------------
// G1: h0proj[b][g] = fc1_b[g] + sum_h h0[b][h] * fc1_w[g][512+h]
// ------------------------------------------------------------------
__global__ __launch_bounds__(256) void g1_kernel(const float* __restrict__ hid,
                                                 const float* __restrict__ fc1_w,
                                                 const float* __restrict__ fc1_b,
                                                 float* __restrict__ h0proj) {
    __shared__ __align__(16) float h0s[Hn];
    int b = blockIdx.x;
    int tid = threadIdx.x;
    for (int i = tid; i < Hn; i += 256) h0s[i] = hid[(size_t)b * 4 * Hn + i];
    __syncthreads();
    for (int g = tid; g < Hn; g += 256) {
        const float* wr = fc1_w + (size_t)g * (Cn + Hn) + Cn;
        float acc = 0.f;
        for (int k = 0; k < Hn; k += 4) {
            float4 w4 = *(const float4*)&wr[k];
            acc = fmaf(w4.x, h0s[k + 0], acc);
            acc = fmaf(w4.y, h0s[k + 1], acc);
            acc = fmaf(w4.z, h0s[k + 2], acc);
            acc = fmaf(w4.w, h0s[k + 3], acc);
        }
        h0proj[b * Hn + g] = acc + fc1_b[g];
    }
}

// ------------------------------------------------------------------
// G2: tb[t][g][b] = bf16( tanh( X[t,b,:512]@fc1_w[g,:512] + h0proj[b][g] ) )
// ------------------------------------------------------------------
__global__ __launch_bounds__(256) void g2_kernel(const float* __restrict__ x,
                                                 const float* __restrict__ fc1_w,
                                                 const float* __restrict__ h0proj,
                                                 __hip_bfloat16* __restrict__ tb) {
    __shared__ __align__(16) float As[64][64];
    __shared__ __align__(16) float Bs[64][64];
    int tid = threadIdx.x;
    int bx = blockIdx.x;
    int g0 = blockIdx.y * 64;
    int ml = tid & 63;
    int kq = tid >> 6;
    const float* xrow = x + (size_t)ml * (Sn * Cn) + (size_t)bx * Cn;
    const float* wrow = fc1_w + (size_t)(g0 + ml) * (Cn + Hn);
    int wave = tid >> 6, lane = tid & 63;
    int tm = (wave & 1) * 32 + (lane & 7) * 4;
    int tg = (wave >> 1) * 32 + (lane >> 3) * 4;
    float acc[4][4] = {};
    for (int kc = 0; kc < Cn / 64; ++kc) {
#pragma unroll
        for (int r = 0; r < 4; ++r) {
            int kk = kq * 16 + r * 4;
            float4 v = *(const float4*)&xrow[kc * 64 + kk];
            As[kk + 0][ml] = v.x; As[kk + 1][ml] = v.y;
            As[kk + 2][ml] = v.z; As[kk + 3][ml] = v.w;
        }
#pragma unroll
        for (int r = 0; r < 4; ++r) {
            int kk = kq * 16 + r * 4;
            float4 v = *(const float4*)&wrow[kc * 64 + kk];
            Bs[kk + 0][ml] = v.x; Bs[kk + 1][ml] = v.y;
            Bs[kk + 2][ml] = v.z; Bs[kk + 3][ml] = v.w;
        }
        __syncthreads();
#pragma unroll 4
        for (int k = 0; k < 64; ++k) {
            float4 a4 = *(const float4*)&As[k][tm];
            float4 b4 = *(const float4*)&Bs[k][tg];
            float av[4] = {a4.x, a4.y, a4.z, a4.w};
            float bv[4] = {b4.x, b4.y, b4.z, b4.w};
#pragma unroll
            for (int i = 0; i < 4; ++i)
#pragma unroll
                for (int j = 0; j < 4; ++j)
                    acc[i][j] = fmaf(av[i], bv[j], acc[i][j]);
        }
        __syncthreads();
    }
#pragma unroll
    for (int j = 0; j < 4; ++j) {
        int g = g0 + tg + j;
        union { ushort4 u4; __hip_bfloat16 h[4]; } cv;
#pragma unroll
        for (int i = 0; i < 4; ++i) {
            float hp = h0proj[(size_t)(tm + i) * Hn + g];
            cv.h[i] = __float2bfloat16(tanhf(acc[i][j] + hp));
        }
        *(ushort4*)&tb[((size_t)bx * Hn + g) * 64 + tm] = cv.u4;
    }
}

// ------------------------------------------------------------------
// G3: logits[m][o] = relu( temp[m][:] @ fc2_w[o][:] + fc2_b[o] )
// ------------------------------------------------------------------
__global__ __launch_bounds__(256) void g3_kernel(const __hip_bfloat16* __restrict__ tb,
                                                 const float* __restrict__ fc2_w,
                                                 const float* __restrict__ fc2_b,
                                                 float* __restrict__ logits) {
    __shared__ __align__(16) float As[64][64];
    __shared__ __align__(16) float Bs[64][64];
    int tid = threadIdx.x;
    int bx = blockIdx.x;
    int g0 = blockIdx.y * 64;
    int ml = tid & 63;
    int kq = tid >> 6;
    const float* wrow = fc2_w + (size_t)(g0 + ml) * Hn;
    int wave = tid >> 6, lane = tid & 63;
    int tm = (wave & 1) * 32 + (lane & 7) * 4;
    int tg = (wave >> 1) * 32 + (lane >> 3) * 4;
    float acc[4][4] = {};
    for (int kc = 0; kc < Hn / 64; ++kc) {
        for (int e = tid; e < 4096; e += 256) {
            int kk = e >> 6, mm = e & 63;
            As[kk][mm] = __bfloat162float(tb[((size_t)bx * Hn + kc * 64 + kk) * 64 + mm]);
        }
#pragma unroll
        for (int r = 0; r < 4; ++r) {
            int kk = kq * 16 + r * 4;
            float4 v = *(const float4*)&wrow[kc * 64 + kk];
            Bs[kk + 0][ml] = v.x; Bs[kk + 1][ml] = v.y;
            Bs[kk + 2][ml] = v.z; Bs[kk + 3][ml] = v.w;
        }
        __syncthreads();
#pragma unroll 4
        for (int k = 0; k < 64; ++k) {
            float4 a4 = *(const float4*)&As[k][tm];
            float4 b4 = *(const float4*)&Bs[k][tg];
            float av[4] = {a4.x, a4.y, a4.z, a4.w};
            float bv[4] = {b4.x, b4.y, b4.z, b4.w};
#pragma unroll
            for (int i = 0; i < 4; ++i)
#pragma unroll
                for (int j = 0; j < 4; ++j)
                    acc[i][j] = fmaf(av[i], bv[j], acc[i][j]);
        }
        __syncthreads();
    }
    int m0 = bx * 64;
#pragma unroll
    for (int i = 0; i < 4; ++i) {
        int m = m0 + tm + i;
        float4 o;
        o.x = fmaxf(acc[i][0] + fc2_b[g0 + tg + 0], 0.f);
        o.y = fmaxf(acc[i][1] + fc2_b[g0 + tg + 1], 0.f);
        o.z = fmaxf(acc[i][2] + fc2_b[g0 + tg + 2], 0.f);
        o.w = fmaxf(acc[i][3] + fc2_b[g0 + tg + 3], 0.f);
        *(float4*)&logits[(size_t)m * Hn + g0 + tg] = o;
    }
}

// ------------------------------------------------------------------
// cvec: out[r] = sum_m A[r][m] * vecB[l(r)*1024 + m] + addB[r]
// ------------------------------------------------------------------
__global__ __launch_bounds__(256) void cvec_kernel(const float* __restrict__ A,
                                                   const float* __restrict__ vecB,
                                                   const float* __restrict__ addB,
                                                   float* __restrict__ outv) {
    int row = blockIdx.x * 4 + (threadIdx.x >> 6);
    int lane = threadIdx.x & 63;
    int l = row >> 10;
    const float* ar = A + (size_t)row * Hn;
    const float* vb = vecB + (size_t)l * Hn;
    float s = 0.f;
#pragma unroll 4
    for (int j = 0; j < 16; ++j) {
        int k = lane + j * 64;
        s = fmaf(ar[k], vb[k], s);
    }
    s += __shfl_xor(s, 1);  s += __shfl_xor(s, 2);  s += __shfl_xor(s, 4);
    s += __shfl_xor(s, 8);  s += __shfl_xor(s, 16); s += __shfl_xor(s, 32);
    if (lane == 0) outv[row] = s + addB[row];
}

// ==================================================================
// gsl3<NC>: C[3072 x NC] = A(16 rows/WG, uniform s_loads) * B (+addRow)
// 192 WGs x 512 thr; 16 rows/WG (layer-clean); thread tile 4r x 2c.
// B: 2 x (32k x NC) LDS dbuf (64KB @NC=256) -> 32 barriers/launch,
// 1024-cyc compute window per chunk (covers L2 latency; T14 prefetch).
// Optional fused fold batch (4 timesteps) at head.
// ==================================================================
template<int NC>
__global__ __launch_bounds__(512, 2) void gsl3_kernel(
        const float* __restrict__ A,          // [3072][1024] flat
        const float* __restrict__ Bsrc,       // + l*bPanel + k*bstride + bcol0
        unsigned long long bPanel, int bstride, int bcol0,
        float* __restrict__ dst, int dstride, int dcol0,
        const float* __restrict__ addRow,     // [3072] or nullptr
        __hip_bfloat16* __restrict__ tb, const float* __restrict__ Xf,
        int folds, int do_gemm) {
    __shared__ __align__(16) float Bsh[2][32][NC];
    const int tid = threadIdx.x;
    const int wg = blockIdx.x;
    const int row0 = wg * 16;
    const int l = row0 >> 10;

    // ---- fused fold(t = 4*folds + tp): temp = tanh(h2+tanh(h1+tanh(h0+t0))) ----
    if (folds >= 0) {
        for (int e = wg * 512 + tid; e < 4 * Hn * Bn; e += 192 * 512) {
            int b = e & 63, g = (e >> 6) & 1023, tp = e >> 16;
            int c = tp * 64 + b;
            size_t tix = ((size_t)(4 * folds + tp) * Hn + g) * 64 + b;
            float tv = __bfloat162float(tb[tix]);
            tv = tanhf(Xf[(size_t)g * 256 + c] + tv);
            tv = tanhf(Xf[262144 + (size_t)g * 256 + c] + tv);
            tv = tanhf(Xf[524288 + (size_t)g * 256 + c] + tv);
            tb[tix] = __float2bfloat16(tv);
        }
    }
    if (!do_gemm) return;

    const int cq = tid & 127;             // col-pair id
    const int rq = tid >> 7;              // 4 row groups (wave-uniform)
    const int rbase = __builtin_amdgcn_readfirstlane(row0 + rq * 4);
    const float* __restrict__ Ar0 = A + (size_t)rbase * 1024;
    const float* __restrict__ Ar1 = Ar0 + 1024;
    const float* __restrict__ Ar2 = Ar0 + 2048;
    const float* __restrict__ Ar3 = Ar0 + 3072;
    const float* __restrict__ Bp = Bsrc + (size_t)l * bPanel + bcol0;
    constexpr int NF4 = NC / 4;           // float4 per k-row
    constexpr int TOT4 = 32 * NF4;        // float4 per chunk (2048 @256, 512 @64)
    constexpr int PFN = (TOT4 + 511) / 512;
    const bool cact = (2 * cq < NC);

    float acc[4][2] = {};
    float4 pf[PFN];

    // stage chunk 0
#pragma unroll
    for (int i = 0; i < PFN; ++i) {
        int e = tid + i * 512;
        int k = e / NF4, c4 = (e % NF4) * 4;
        pf[i] = *(const float4*)(Bp + (size_t)k * bstride + c4);
    }
#pragma unroll
    for (int i = 0; i < PFN; ++i) {
        int e = tid + i * 512;
        int k = e / NF4, c4 = (e % NF4) * 4;
        *(float4*)&Bsh[0][k][c4] = pf[i];
    }
    __syncthreads();

    for (int ck = 0; ck < 32; ++ck) {
        if (ck < 31) {                    // T14: issue next-chunk loads early
#pragma unroll
            for (int i = 0; i < PFN; ++i) {
                int e = tid + i * 512;
                int k = e / NF4, c4 = (e % NF4) * 4;
                pf[i] = *(const float4*)(Bp + (size_t)((ck + 1) * 32 + k) * bstride + c4);
            }
        }
        if (cact) {
            const float* bsc = &Bsh[ck & 1][0][2 * cq];
            const int k0 = ck * 32;
#pragma unroll 16
            for (int kk = 0; kk < 32; ++kk) {
                float2 b2 = *(const float2*)(bsc + kk * NC);
                float w0 = Ar0[k0 + kk];
                float w1 = Ar1[k0 + kk];
                float w2v = Ar2[k0 + kk];
                float w3 = Ar3[k0 + kk];
                acc[0][0] = fmaf(w0, b2.x, acc[0][0]);
                acc[0][1] = fmaf(w0, b2.y, acc[0][1]);
                acc[1][0] = fmaf(w1, b2.x, acc[1][0]);
                acc[1][1] = fmaf(w1, b2.y, acc[1][1]);
                acc[2][0] = fmaf(w2v, b2.x, acc[2][0]);
                acc[2][1] = fmaf(w2v, b2.y, acc[2][1]);
                acc[3][0] = fmaf(w3, b2.x, acc[3][0]);
                acc[3][1] = fmaf(w3, b2.y, acc[3][1]);
            }
        }
        if (ck < 31) {
#pragma unroll
            for (int i = 0; i < PFN; ++i) {
                int e = tid + i * 512;
                int k = e / NF4, c4 = (e % NF4) * 4;
                *(float4*)&Bsh[(ck + 1) & 1][k][c4] = pf[i];
            }
            __syncthreads();
        }
    }

    if (cact) {
#pragma unroll
        for (int i = 0; i < 4; ++i) {
            int r = rbase + i;
            float av = addRow ? addRow[r] : 0.0f;
            float2 o = make_float2(acc[i][0] + av, acc[i][1] + av);
            *(float2*)(dst + (size_t)r * dstride + dcol0 + 2 * cq) = o;
        }
    }
}

// ------------------------------------------------------------------
// softmax over each 1024-row of logits -> f32 out
// ------------------------------------------------------------------
__global__ __launch_bounds__(256) void softmax_kernel(const float* __restrict__ logits,
                                                      float* __restrict__ out) {
    __shared__ float redm[4];
    __shared__ float reds[4];
    __shared__ float bcast[2];
    int row = blockIdx.x, tid = threadIdx.x;
    const float* in = logits + (size_t)row * On;
    float4 v = *(const float4*)&in[tid * 4];
    float mx = fmaxf(fmaxf(v.x, v.y), fmaxf(v.z, v.w));
#pragma unroll
    for (int o = 32; o > 0; o >>= 1) mx = fmaxf(mx, __shfl_down(mx, o));
    if ((tid & 63) == 0) redm[tid >> 6] = mx;
    __syncthreads();
    if (tid == 0) bcast[0] = fmaxf(fmaxf(redm[0], redm[1]), fmaxf(redm[2], redm[3]));
    __syncthreads();
    float M = bcast[0];
    float e0 = expf(v.x - M), e1 = expf(v.y - M), e2 = expf(v.z - M), e3 = expf(v.w - M);
    float s = e0 + e1 + e2 + e3;
#pragma unroll
    for (int o = 32; o > 0; o >>= 1) s += __shfl_down(s, o);
    if ((tid & 63) == 0) reds[tid >> 6] = s;
    __syncthreads();
    if (tid == 0) bcast[1] = reds[0] + reds[1] + reds[2] + reds[3];
    __syncthreads();
    float inv = 1.0f / bcast[1];
    float4 o4 = make_float4(e0 * inv, e1 * inv, e2 * inv, e3 * inv);
    *(float4*)&out[(size_t)row * On + tid * 4] = o4;
}

// ------------------------------------------------------------------
extern "C" void kernel_launch(void* const* d_in, const int* in_sizes, int n_in,
                              void* d_out, int out_size, void* d_ws, size_t ws_size,
                              hipStream_t stream) {
    const float* x     = (const float*)d_in[0];
    const float* hid   = (const float*)d_in[1];
    const float* fc1_w = (const float*)d_in[2];
    const float* fc1_b = (const float*)d_in[3];
    const float* fc2_w = (const float*)d_in[4];
    const float* fc2_b = (const float*)d_in[5];
    const float* lin_w = (const float*)d_in[6];
    const float* lin_b = (const float*)d_in[7];
    float* out = (float*)d_out;

    char* wsb = (char*)d_ws;
    __hip_bfloat16* tb = (__hip_bfloat16*)wsb;            // 32 MB  [t][g][b]
    float* logits = (float*)(wsb + 33554432ull);          // 64 MB
    float* w2     = (float*)(wsb + 100663296ull);         // 12 MB [3072][1024]
    float* w4     = (float*)(wsb + 113246208ull);         // 12 MB
    float* X      = (float*)(wsb + 125829120ull);         // 2 x 3 MB [l][g][256]
    float* c2     = (float*)(wsb + 132120576ull);         // 12 KB
    float* c4     = (float*)(wsb + 132132864ull);         // 12 KB
    float* h0T    = (float*)(wsb + 132145152ull);         // 768 KB [l][k][64]
    float* h0proj = (float*)(wsb + 132931584ull);         // 256 KB

    float* X0 = X;
    float* X1 = X + 786432;

    prep_kernel<<<48, 256, 0, stream>>>(hid, h0T);
    g1_kernel<<<Bn, 256, 0, stream>>>(hid, fc1_w, fc1_b, h0proj);
    g2_kernel<<<dim3(Sn, Hn / 64), 256, 0, stream>>>(x, fc1_w, h0proj, tb);

    // c2 = W b + b
    cvec_kernel<<<768, 256, 0, stream>>>(lin_w, lin_b, lin_b, c2);
    // W2 = W * W  (4 col passes)
    for (int p = 0; p < 4; ++p)
        gsl3_kernel<256><<<192, 512, 0, stream>>>(lin_w, lin_w, 1048576ull, 1024, p * 256,
                                                  w2, 1024, p * 256, nullptr,
                                                  tb, nullptr, -1, 1);
    // c4 = W2 c2 + c2
    cvec_kernel<<<768, 256, 0, stream>>>(w2, c2, c2, c4);
    // W4 = W2 * W2
    for (int p = 0; p < 4; ++p)
        gsl3_kernel<256><<<192, 512, 0, stream>>>(w2, w2, 1048576ull, 1024, p * 256,
                                                  w4, 1024, p * 256, nullptr,
                                                  tb, nullptr, -1, 1);
    // seeds into X0: h1 | h2 | h3 | h4  (cols 0,64,128,192)
    gsl3_kernel<64><<<192, 512, 0, stream>>>(lin_w, h0T, 65536ull, 64, 0,
                                             X0, 256, 0, lin_b, tb, nullptr, -1, 1);
    gsl3_kernel<64><<<192, 512, 0, stream>>>(w2, h0T, 65536ull, 64, 0,
                                             X0, 256, 64, c2, tb, nullptr, -1, 1);
    gsl3_kernel<64><<<192, 512, 0, stream>>>(w4, h0T, 65536ull, 64, 0,
                                             X0, 256, 192, c4, tb, nullptr, -1, 1);
    gsl3_kernel<64><<<192, 512, 0, stream>>>(w2, X0, 262144ull, 256, 0,
                                             X0, 256, 128, c2, tb, nullptr, -1, 1);

    // main: 63 supersteps (X_{s+1} = W4 X_s + c4) with fused fold(batch s)
    for (int s = 0; s < 63; ++s) {
        float* Xin  = (s & 1) ? X1 : X0;
        float* Xout = (s & 1) ? X0 : X1;
        gsl3_kernel<256><<<192, 512, 0, stream>>>(w4, Xin, 262144ull, 256, 0,
                                                  Xout, 256, 0, c4, tb, Xin, s, 1);
    }
    // final fold batch 63 (state in X1)
    gsl3_kernel<256><<<192, 512, 0, stream>>>(w4, X1, 262144ull, 256, 0,
                                              X0, 256, 0, c4, tb, X1, 63, 0);

    g3_kernel<<<dim3(Sn, Hn / 64), 256, 0, stream>>>(tb, fc2_w, fc2_b, logits);
    softmax_kernel<<<Sn * Bn, 256, 0, stream>>>(logits, out);
}

// Round 9
// 5033.590 us; speedup vs baseline: 1.5990x; 1.4164x over previous
//
#include <hip/hip_runtime.h>
#include <hip/hip_bf16.h>

#define Bn 64
#define Sn 256
#define Cn 512
#define Hn 1024
#define On 1024
#define NL 3

// ------------------------------------------------------------------
// prep: h0T[l][k][b] = hid[b][l+1][k]  (64x64 LDS tile transpose)
// ------------------------------------------------------------------
__global__ __launch_bounds__(256) void prep_kernel(const float* __restrict__ hid,
                                                   float* __restrict__ h0T) {
    __shared__ float T[64][65];
    int l = blockIdx.x >> 4;
    int kb = (blockIdx.x & 15) * 64;
    int tid = threadIdx.x;
    for (int e = tid; e < 1024; e += 256) {
        int b = e >> 4, k4 = (e & 15) * 4;
        float4 v = *(const float4*)&hid[(size_t)b * 4096 + (size_t)(l + 1) * 1024 + kb + k4];
        T[b][k4] = v.x; T[b][k4 + 1] = v.y; T[b][k4 + 2] = v.z; T[b][k4 + 3] = v.w;
    }
    __syncthreads();
    for (int e = tid; e < 1024; e += 256) {
        int k = e >> 4, b4 = (e & 15) * 4;
        float4 v = make_float4(T[b4][k], T[b4 + 1][k], T[b4 + 2][k], T[b4 + 3][k]);
        *(float4*)&h0T[(size_t)l * 65536 + (size_t)(kb + k) * 64 + b4] = v;
    }
}

// ------------------------------------------------------------------
// G1: h0proj[b][g] = fc1_b[g] + sum_h h0[b][h] * fc1_w[g][512+h]
// ------------------------------------------------------------------
__global__ __launch_bounds__(256) void g1_kernel(const float* __restrict__ hid,
                                                 const float* __restrict__ fc1_w,
                                                 const float* __restrict__ fc1_b,
                                                 float* __restrict__ h0proj) {
    __shared__ __align__(16) float h0s[Hn];
    int b = blockIdx.x;
    int tid = threadIdx.x;
    for (int i = tid; i < Hn; i += 256) h0s[i] = hid[(size_t)b * 4 * Hn + i];
    __syncthreads();
    for (int g = tid; g < Hn; g += 256) {
        const float* wr = fc1_w + (size_t)g * (Cn + Hn) + Cn;
        float acc = 0.f;
        for (int k = 0; k < Hn; k += 4) {
            float4 w4 = *(const float4*)&wr[k];
            acc = fmaf(w4.x, h0s[k + 0], acc);
            acc = fmaf(w4.y, h0s[k + 1], acc);
            acc = fmaf(w4.z, h0s[k + 2], acc);
            acc = fmaf(w4.w, h0s[k + 3], acc);
        }
        h0proj[b * Hn + g] = acc + fc1_b[g];
    }
}

// ------------------------------------------------------------------
// G2: tb[t][g][b] = bf16( tanh( X[t,b,:512]@fc1_w[g,:512] + h0proj[b][g] ) )
// ------------------------------------------------------------------
__global__ __launch_bounds__(256) void g2_kernel(const float* __restrict__ x,
                                                 const float* __restrict__ fc1_w,
                                                 const float* __restrict__ h0proj,
                                                 __hip_bfloat16* __restrict__ tb) {
    __shared__ __align__(16) float As[64][64];
    __shared__ __align__(16) float Bs[64][64];
    int tid = threadIdx.x;
    int bx = blockIdx.x;
    int g0 = blockIdx.y * 64;
    int ml = tid & 63;
    int kq = tid >> 6;
    const float* xrow = x + (size_t)ml * (Sn * Cn) + (size_t)bx * Cn;
    const float* wrow = fc1_w + (size_t)(g0 + ml) * (Cn + Hn);
    int wave = tid >> 6, lane = tid & 63;
    int tm = (wave & 1) * 32 + (lane & 7) * 4;
    int tg = (wave >> 1) * 32 + (lane >> 3) * 4;
    float acc[4][4] = {};
    for (int kc = 0; kc < Cn / 64; ++kc) {
#pragma unroll
        for (int r = 0; r < 4; ++r) {
            int kk = kq * 16 + r * 4;
            float4 v = *(const float4*)&xrow[kc * 64 + kk];
            As[kk + 0][ml] = v.x; As[kk + 1][ml] = v.y;
            As[kk + 2][ml] = v.z; As[kk + 3][ml] = v.w;
        }
#pragma unroll
        for (int r = 0; r < 4; ++r) {
            int kk = kq * 16 + r * 4;
            float4 v = *(const float4*)&wrow[kc * 64 + kk];
            Bs[kk + 0][ml] = v.x; Bs[kk + 1][ml] = v.y;
            Bs[kk + 2][ml] = v.z; Bs[kk + 3][ml] = v.w;
        }
        __syncthreads();
#pragma unroll 4
        for (int k = 0; k < 64; ++k) {
            float4 a4 = *(const float4*)&As[k][tm];
            float4 b4 = *(const float4*)&Bs[k][tg];
            float av[4] = {a4.x, a4.y, a4.z, a4.w};
            float bv[4] = {b4.x, b4.y, b4.z, b4.w};
#pragma unroll
            for (int i = 0; i < 4; ++i)
#pragma unroll
                for (int j = 0; j < 4; ++j)
                    acc[i][j] = fmaf(av[i], bv[j], acc[i][j]);
        }
        __syncthreads();
    }
#pragma unroll
    for (int j = 0; j < 4; ++j) {
        int g = g0 + tg + j;
        union { ushort4 u4; __hip_bfloat16 h[4]; } cv;
#pragma unroll
        for (int i = 0; i < 4; ++i) {
            float hp = h0proj[(size_t)(tm + i) * Hn + g];
            cv.h[i] = __float2bfloat16(tanhf(acc[i][j] + hp));
        }
        *(ushort4*)&tb[((size_t)bx * Hn + g) * 64 + tm] = cv.u4;
    }
}

// ------------------------------------------------------------------
// G3: logits[m][o] = relu( temp[m][:] @ fc2_w[o][:] + fc2_b[o] )
// ------------------------------------------------------------------
__global__ __launch_bounds__(256) void g3_kernel(const __hip_bfloat16* __restrict__ tb,
                                                 const float* __restrict__ fc2_w,
                                                 const float* __restrict__ fc2_b,
                                                 float* __restrict__ logits) {
    __shared__ __align__(16) float As[64][64];
    __shared__ __align__(16) float Bs[64][64];
    int tid = threadIdx.x;
    int bx = blockIdx.x;
    int g0 = blockIdx.y * 64;
    int ml = tid & 63;
    int kq = tid >> 6;
    const float* wrow = fc2_w + (size_t)(g0 + ml) * Hn;
    int wave = tid >> 6, lane = tid & 63;
    int tm = (wave & 1) * 32 + (lane & 7) * 4;
    int tg = (wave >> 1) * 32 + (lane >> 3) * 4;
    float acc[4][4] = {};
    for (int kc = 0; kc < Hn / 64; ++kc) {
        for (int e = tid; e < 4096; e += 256) {
            int kk = e >> 6, mm = e & 63;
            As[kk][mm] = __bfloat162float(tb[((size_t)bx * Hn + kc * 64 + kk) * 64 + mm]);
        }
#pragma unroll
        for (int r = 0; r < 4; ++r) {
            int kk = kq * 16 + r * 4;
            float4 v = *(const float4*)&wrow[kc * 64 + kk];
            Bs[kk + 0][ml] = v.x; Bs[kk + 1][ml] = v.y;
            Bs[kk + 2][ml] = v.z; Bs[kk + 3][ml] = v.w;
        }
        __syncthreads();
#pragma unroll 4
        for (int k = 0; k < 64; ++k) {
            float4 a4 = *(const float4*)&As[k][tm];
            float4 b4 = *(const float4*)&Bs[k][tg];
            float av[4] = {a4.x, a4.y, a4.z, a4.w};
            float bv[4] = {b4.x, b4.y, b4.z, b4.w};
#pragma unroll
            for (int i = 0; i < 4; ++i)
#pragma unroll
                for (int j = 0; j < 4; ++j)
                    acc[i][j] = fmaf(av[i], bv[j], acc[i][j]);
        }
        __syncthreads();
    }
    int m0 = bx * 64;
#pragma unroll
    for (int i = 0; i < 4; ++i) {
        int m = m0 + tm + i;
        float4 o;
        o.x = fmaxf(acc[i][0] + fc2_b[g0 + tg + 0], 0.f);
        o.y = fmaxf(acc[i][1] + fc2_b[g0 + tg + 1], 0.f);
        o.z = fmaxf(acc[i][2] + fc2_b[g0 + tg + 2], 0.f);
        o.w = fmaxf(acc[i][3] + fc2_b[g0 + tg + 3], 0.f);
        *(float4*)&logits[(size_t)m * Hn + g0 + tg] = o;
    }
}

// ------------------------------------------------------------------
// cvec: out[r] = sum_m A[r][m] * vecB[l(r)*1024 + m] + addB[r]
// ------------------------------------------------------------------
__global__ __launch_bounds__(256) void cvec_kernel(const float* __restrict__ A,
                                                   const float* __restrict__ vecB,
                                                   const float* __restrict__ addB,
                                                   float* __restrict__ outv) {
    int row = blockIdx.x * 4 + (threadIdx.x >> 6);
    int lane = threadIdx.x & 63;
    int l = row >> 10;
    const float* ar = A + (size_t)row * Hn;
    const float* vb = vecB + (size_t)l * Hn;
    float s = 0.f;
#pragma unroll 4
    for (int j = 0; j < 16; ++j) {
        int k = lane + j * 64;
        s = fmaf(ar[k], vb[k], s);
    }
    s += __shfl_xor(s, 1);  s += __shfl_xor(s, 2);  s += __shfl_xor(s, 4);
    s += __shfl_xor(s, 8);  s += __shfl_xor(s, 16); s += __shfl_xor(s, 32);
    if (lane == 0) outv[row] = s + addB[row];
}

// ==================================================================
// gsl4<NC>: C[3072 x NC] = A * B (+addRow). r6 shape, A now in LDS.
// 192 WGs x 512 thr; 16 rows/WG (layer-clean); tile 4r x 2c.
// 64 chunks x 16k. LDS: As[2][16][16] (A transposed, broadcast b128
// reads) + Xs[2][16][NC]; both reg-prefetched one chunk ahead (T14).
// Optional fused fold batch (4 timesteps) at head.
// ==================================================================
template<int NC>
__global__ __launch_bounds__(512, 2) void gsl4_kernel(
        const float* __restrict__ A,          // [3072][1024] flat
        const float* __restrict__ Bsrc,       // + l*bPanel + k*bstride + bcol0
        unsigned long long bPanel, int bstride, int bcol0,
        float* __restrict__ dst, int dstride, int dcol0,
        const float* __restrict__ addRow,     // [3072] or nullptr
        __hip_bfloat16* __restrict__ tb, const float* __restrict__ Xf,
        int folds, int do_gemm) {
    __shared__ __align__(16) float As[2][16][16];
    __shared__ __align__(16) float Xs[2][16][NC];
    const int tid = threadIdx.x;
    const int wg = blockIdx.x;
    const int row0 = wg * 16;
    const int l = row0 >> 10;

    // ---- fused fold(t = 4*folds + tp): temp = tanh(h2+tanh(h1+tanh(h0+t0))) ----
    if (folds >= 0) {
        for (int e = wg * 512 + tid; e < 4 * Hn * Bn; e += 192 * 512) {
            int b = e & 63, g = (e >> 6) & 1023, tp = e >> 16;
            int c = tp * 64 + b;
            size_t tix = ((size_t)(4 * folds + tp) * Hn + g) * 64 + b;
            float tv = __bfloat162float(tb[tix]);
            tv = tanhf(Xf[(size_t)g * 256 + c] + tv);
            tv = tanhf(Xf[262144 + (size_t)g * 256 + c] + tv);
            tv = tanhf(Xf[524288 + (size_t)g * 256 + c] + tv);
            tb[tix] = __float2bfloat16(tv);
        }
    }
    if (!do_gemm) return;

    const int cq = tid & 127;             // col-pair id
    const int rq = tid >> 7;              // 4 row groups of 4 rows (wave-uniform)
    const float* __restrict__ Bp = Bsrc + (size_t)l * bPanel + bcol0;
    constexpr int NF4 = NC / 4;           // float4 per k-row
    constexpr int TOT4 = 16 * NF4;        // float4 per X chunk
    constexpr int PFN = (TOT4 + 511) / 512;
    const bool cact = (2 * cq < NC);
    // A-stage mapping (threads 0..63): row = t&15, kq = t>>4 (4 k-quads)
    const int arow = tid & 15, akq = tid >> 4;
    const bool aact = (tid < 64);

    float acc[4][2] = {};
    float4 px[PFN];
    float4 pa;

    // ---- stage chunk 0 ----
#pragma unroll
    for (int i = 0; i < PFN; ++i) {
        int e = tid + i * 512;
        if ((TOT4 % 512 == 0) || e < TOT4) {
            int k = e / NF4, c4 = (e % NF4) * 4;
            px[i] = *(const float4*)(Bp + (size_t)k * bstride + c4);
        }
    }
    if (aact)
        pa = *(const float4*)(A + (size_t)(row0 + arow) * 1024 + akq * 4);
#pragma unroll
    for (int i = 0; i < PFN; ++i) {
        int e = tid + i * 512;
        if ((TOT4 % 512 == 0) || e < TOT4) {
            int k = e / NF4, c4 = (e % NF4) * 4;
            *(float4*)&Xs[0][k][c4] = px[i];
        }
    }
    if (aact) {
        As[0][akq * 4 + 0][arow] = pa.x;
        As[0][akq * 4 + 1][arow] = pa.y;
        As[0][akq * 4 + 2][arow] = pa.z;
        As[0][akq * 4 + 3][arow] = pa.w;
    }
    __syncthreads();

    for (int ck = 0; ck < 64; ++ck) {
        if (ck < 63) {                    // T14: issue next-chunk loads early
#pragma unroll
            for (int i = 0; i < PFN; ++i) {
                int e = tid + i * 512;
                if ((TOT4 % 512 == 0) || e < TOT4) {
                    int k = e / NF4, c4 = (e % NF4) * 4;
                    px[i] = *(const float4*)(Bp + (size_t)((ck + 1) * 16 + k) * bstride + c4);
                }
            }
            if (aact)
                pa = *(const float4*)(A + (size_t)(row0 + arow) * 1024 + (ck + 1) * 16 + akq * 4);
        }
        if (cact) {
            const float* xsc = &Xs[ck & 1][0][2 * cq];
            const float* asc = &As[ck & 1][0][rq * 4];
#pragma unroll
            for (int kk = 0; kk < 16; ++kk) {
                float4 a4 = *(const float4*)(asc + kk * 16);   // broadcast b128
                float2 x2 = *(const float2*)(xsc + kk * NC);
                acc[0][0] = fmaf(a4.x, x2.x, acc[0][0]);
                acc[0][1] = fmaf(a4.x, x2.y, acc[0][1]);
                acc[1][0] = fmaf(a4.y, x2.x, acc[1][0]);
                acc[1][1] = fmaf(a4.y, x2.y, acc[1][1]);
                acc[2][0] = fmaf(a4.z, x2.x, acc[2][0]);
                acc[2][1] = fmaf(a4.z, x2.y, acc[2][1]);
                acc[3][0] = fmaf(a4.w, x2.x, acc[3][0]);
                acc[3][1] = fmaf(a4.w, x2.y, acc[3][1]);
            }
        }
        if (ck < 63) {
#pragma unroll
            for (int i = 0; i < PFN; ++i) {
                int e = tid + i * 512;
                if ((TOT4 % 512 == 0) || e < TOT4) {
                    int k = e / NF4, c4 = (e % NF4) * 4;
                    *(float4*)&Xs[(ck + 1) & 1][k][c4] = px[i];
                }
            }
            if (aact) {
                As[(ck + 1) & 1][akq * 4 + 0][arow] = pa.x;
                As[(ck + 1) & 1][akq * 4 + 1][arow] = pa.y;
                As[(ck + 1) & 1][akq * 4 + 2][arow] = pa.z;
                As[(ck + 1) & 1][akq * 4 + 3][arow] = pa.w;
            }
            __syncthreads();
        }
    }

    if (cact) {
#pragma unroll
        for (int i = 0; i < 4; ++i) {
            int r = row0 + rq * 4 + i;
            float av = addRow ? addRow[r] : 0.0f;
            float2 o = make_float2(acc[i][0] + av, acc[i][1] + av);
            *(float2*)(dst + (size_t)r * dstride + dcol0 + 2 * cq) = o;
        }
    }
}

// ------------------------------------------------------------------
// softmax over each 1024-row of logits -> f32 out
// ------------------------------------------------------------------
__global__ __launch_bounds__(256) void softmax_kernel(const float* __restrict__ logits,
                                                      float* __restrict__ out) {
    __shared__ float redm[4];
    __shared__ float reds[4];
    __shared__ float bcast[2];
    int row = blockIdx.x, tid = threadIdx.x;
    const float* in = logits + (size_t)row * On;
    float4 v = *(const float4*)&in[tid * 4];
    float mx = fmaxf(fmaxf(v.x, v.y), fmaxf(v.z, v.w));
#pragma unroll
    for (int o = 32; o > 0; o >>= 1) mx = fmaxf(mx, __shfl_down(mx, o));
    if ((tid & 63) == 0) redm[tid >> 6] = mx;
    __syncthreads();
    if (tid == 0) bcast[0] = fmaxf(fmaxf(redm[0], redm[1]), fmaxf(redm[2], redm[3]));
    __syncthreads();
    float M = bcast[0];
    float e0 = expf(v.x - M), e1 = expf(v.y - M), e2 = expf(v.z - M), e3 = expf(v.w - M);
    float s = e0 + e1 + e2 + e3;
#pragma unroll
    for (int o = 32; o > 0; o >>= 1) s += __shfl_down(s, o);
    if ((tid & 63) == 0) reds[tid >> 6] = s;
    __syncthreads();
    if (tid == 0) bcast[1] = reds[0] + reds[1] + reds[2] + reds[3];
    __syncthreads();
    float inv = 1.0f / bcast[1];
    float4 o4 = make_float4(e0 * inv, e1 * inv, e2 * inv, e3 * inv);
    *(float4*)&out[(size_t)row * On + tid * 4] = o4;
}

// ------------------------------------------------------------------
extern "C" void kernel_launch(void* const* d_in, const int* in_sizes, int n_in,
                              void* d_out, int out_size, void* d_ws, size_t ws_size,
                              hipStream_t stream) {
    const float* x     = (const float*)d_in[0];
    const float* hid   = (const float*)d_in[1];
    const float* fc1_w = (const float*)d_in[2];
    const float* fc1_b = (const float*)d_in[3];
    const float* fc2_w = (const float*)d_in[4];
    const float* fc2_b = (const float*)d_in[5];
    const float* lin_w = (const float*)d_in[6];
    const float* lin_b = (const float*)d_in[7];
    float* out = (float*)d_out;

    char* wsb = (char*)d_ws;
    __hip_bfloat16* tb = (__hip_bfloat16*)wsb;            // 32 MB  [t][g][b]
    float* logits = (float*)(wsb + 33554432ull);          // 64 MB
    float* w2     = (float*)(wsb + 100663296ull);         // 12 MB [3072][1024]
    float* w4     = (float*)(wsb + 113246208ull);         // 12 MB
    float* X      = (float*)(wsb + 125829120ull);         // 2 x 3 MB [l][g][256]
    float* c2     = (float*)(wsb + 132120576ull);         // 12 KB
    float* c4     = (float*)(wsb + 132132864ull);         // 12 KB
    float* h0T    = (float*)(wsb + 132145152ull);         // 768 KB [l][k][64]
    float* h0proj = (float*)(wsb + 132931584ull);         // 256 KB

    float* X0 = X;
    float* X1 = X + 786432;

    prep_kernel<<<48, 256, 0, stream>>>(hid, h0T);
    g1_kernel<<<Bn, 256, 0, stream>>>(hid, fc1_w, fc1_b, h0proj);
    g2_kernel<<<dim3(Sn, Hn / 64), 256, 0, stream>>>(x, fc1_w, h0proj, tb);

    // c2 = W b + b
    cvec_kernel<<<768, 256, 0, stream>>>(lin_w, lin_b, lin_b, c2);
    // W2 = W * W  (4 col passes)
    for (int p = 0; p < 4; ++p)
        gsl4_kernel<256><<<192, 512, 0, stream>>>(lin_w, lin_w, 1048576ull, 1024, p * 256,
                                                  w2, 1024, p * 256, nullptr,
                                                  tb, nullptr, -1, 1);
    // c4 = W2 c2 + c2
    cvec_kernel<<<768, 256, 0, stream>>>(w2, c2, c2, c4);
    // W4 = W2 * W2
    for (int p = 0; p < 4; ++p)
        gsl4_kernel<256><<<192, 512, 0, stream>>>(w2, w2, 1048576ull, 1024, p * 256,
                                                  w4, 1024, p * 256, nullptr,
                                                  tb, nullptr, -1, 1);
    // seeds into X0: h1 | h2 | h3 | h4  (cols 0,64,128,192)
    gsl4_kernel<64><<<192, 512, 0, stream>>>(lin_w, h0T, 65536ull, 64, 0,
                                             X0, 256, 0, lin_b, tb, nullptr, -1, 1);
    gsl4_kernel<64><<<192, 512, 0, stream>>>(w2, h0T, 65536ull, 64, 0,
                                             X0, 256, 64, c2, tb, nullptr, -1, 1);
    gsl4_kernel<64><<<192, 512, 0, stream>>>(w4, h0T, 65536ull, 64, 0,
                                             X0, 256, 192, c4, tb, nullptr, -1, 1);
    gsl4_kernel<64><<<192, 512, 0, stream>>>(w2, X0, 262144ull, 256, 0,
                                             X0, 256, 128, c2, tb, nullptr, -1, 1);

    // main: 63 supersteps (X_{s+1} = W4 X_s + c4) with fused fold(batch s)
    for (int s = 0; s < 63; ++s) {
        float* Xin  = (s & 1) ? X1 : X0;
        float* Xout = (s & 1) ? X0 : X1;
        gsl4_kernel<256><<<192, 512, 0, stream>>>(w4, Xin, 262144ull, 256, 0,
                                                  Xout, 256, 0, c4, tb, Xin, s, 1);
    }
    // final fold batch 63 (state in X1)
    gsl4_kernel<256><<<192, 512, 0, stream>>>(w4, X1, 262144ull, 256, 0,
                                              X0, 256, 0, c4, tb, X1, 63, 0);

    g3_kernel<<<dim3(Sn, Hn / 64), 256, 0, stream>>>(tb, fc2_w, fc2_b, logits);
    softmax_kernel<<<Sn * Bn, 256, 0, stream>>>(logits, out);
}